// Round 1
// baseline (583.488 us; speedup 1.0000x reference)
//
#include <hip/hip_runtime.h>
#include <float.h>

#define NUM_EMB 512
#define DIM     128
#define HW      4096          // 64*64 spatial per batch
#define NPOS    (32 * 4096)   // 131072 positions

// --- prologue: e_sq[k] = ||embedding[k]||^2 (fp32) --------------------------
__global__ void esq_kernel(const float* __restrict__ emb, float* __restrict__ e_sq) {
    int k = blockIdx.x * blockDim.x + threadIdx.x;
    if (k < NUM_EMB) {
        const float4* row = (const float4*)(emb + k * DIM);
        float s0 = 0.f, s1 = 0.f, s2 = 0.f, s3 = 0.f;
        #pragma unroll
        for (int c = 0; c < DIM / 4; ++c) {
            float4 v = row[c];
            s0 = fmaf(v.x, v.x, s0);
            s1 = fmaf(v.y, v.y, s1);
            s2 = fmaf(v.z, v.z, s2);
            s3 = fmaf(v.w, v.w, s3);
        }
        e_sq[k] = (s0 + s1) + (s2 + s3);
    }
}

// --- main: per-position argmin over 512 codes + fused gather-write ----------
// z layout: (b, c, hw) -> z[b*DIM*HW + c*HW + hw]; position n = b*HW + hw.
// For fixed c, consecutive lanes (consecutive hw) read consecutive floats:
// fully coalesced. Embedding rows are wave-uniform -> scalar (s_load) reads.
__global__ __launch_bounds__(256) void vq_kernel(const float* __restrict__ z,
                                                 const float* __restrict__ emb,
                                                 const float* __restrict__ e_sq,
                                                 float* __restrict__ out) {
    int n  = blockIdx.x * 256 + threadIdx.x;
    int b  = n >> 12;          // n / 4096
    int hw = n & 4095;

    const float* zb = z + (size_t)b * DIM * HW + hw;
    float zr[DIM];
    #pragma unroll
    for (int c = 0; c < DIM; ++c) zr[c] = zb[(size_t)c * HW];

    float best  = FLT_MAX;
    int   besti = 0;
    for (int k = 0; k < NUM_EMB; ++k) {
        const float4* er = (const float4*)(emb + k * DIM);
        float d0 = 0.f, d1 = 0.f, d2 = 0.f, d3 = 0.f;
        #pragma unroll
        for (int c = 0; c < DIM / 4; ++c) {
            float4 e = er[c];
            d0 = fmaf(zr[4 * c + 0], e.x, d0);
            d1 = fmaf(zr[4 * c + 1], e.y, d1);
            d2 = fmaf(zr[4 * c + 2], e.z, d2);
            d3 = fmaf(zr[4 * c + 3], e.w, d3);
        }
        // s = ||e_k||^2 - 2 z.e_k  (drop ||z||^2: constant per position)
        float s = e_sq[k] - 2.f * ((d0 + d1) + (d2 + d3));
        if (s < best) { best = s; besti = k; }   // strict <: first-min tie-break, matches np.argmin
    }

    // fused gather: out[b, c, hw] = emb[besti, c]; per-c writes are coalesced,
    // per-lane 16B gather reads hit L2 (embedding = 256 KB, L2-resident).
    float* ob = out + (size_t)b * DIM * HW + hw;
    const float4* sel = (const float4*)(emb + (size_t)besti * DIM);
    #pragma unroll
    for (int c4 = 0; c4 < DIM / 4; ++c4) {
        float4 v = sel[c4];
        ob[(size_t)(4 * c4 + 0) * HW] = v.x;
        ob[(size_t)(4 * c4 + 1) * HW] = v.y;
        ob[(size_t)(4 * c4 + 2) * HW] = v.z;
        ob[(size_t)(4 * c4 + 3) * HW] = v.w;
    }
}

extern "C" void kernel_launch(void* const* d_in, const int* in_sizes, int n_in,
                              void* d_out, int out_size, void* d_ws, size_t ws_size,
                              hipStream_t stream) {
    const float* z   = (const float*)d_in[0];   // (32,128,64,64) fp32
    const float* emb = (const float*)d_in[1];   // (512,128) fp32
    float* out  = (float*)d_out;                // (32,128,64,64) fp32
    float* e_sq = (float*)d_ws;                 // 512 floats scratch

    esq_kernel<<<(NUM_EMB + 255) / 256, 256, 0, stream>>>(emb, e_sq);
    vq_kernel<<<NPOS / 256, 256, 0, stream>>>(z, emb, e_sq, out);
}